// Round 6
// baseline (321.882 us; speedup 1.0000x reference)
//
#include <hip/hip_runtime.h>

#define B_ 16
#define S_ 1024
#define E_ 512
#define H_ 8
#define D_ 64
#define L_ 4
#define M_ (B_*S_)   // 16384 tokens

typedef unsigned short u16;
typedef __attribute__((ext_vector_type(8))) short bf16x8;  // 8 bf16 = 4 VGPRs
typedef __attribute__((ext_vector_type(4))) float f32x4;
typedef __attribute__((ext_vector_type(4))) unsigned uint4v;

__device__ __forceinline__ u16 f2bf(float x) {
  unsigned u = __float_as_uint(x);
  unsigned r = (u + 0x7fffu + ((u >> 16) & 1u)) >> 16;  // RNE
  return (u16)r;
}
__device__ __forceinline__ ushort4 f2bf4(float4 f) {
  ushort4 u;
  u.x = f2bf(f.x); u.y = f2bf(f.y); u.z = f2bf(f.z); u.w = f2bf(f.w);
  return u;
}
// pack two f32 -> two bf16 (round-half-up, err <= 0.5 ulp); lo in low half
__device__ __forceinline__ unsigned pk_bf16(float lo, float hi) {
  unsigned ul = __float_as_uint(lo) + 0x8000u;
  unsigned uh = __float_as_uint(hi) + 0x8000u;
#if __has_builtin(__builtin_amdgcn_perm)
  return __builtin_amdgcn_perm(uh, ul, 0x07060302u);  // {uh.b3,uh.b2,ul.b3,ul.b2}
#else
  return (ul >> 16) | (uh & 0xffff0000u);
#endif
}

typedef __attribute__((address_space(1))) const void gconst_void;
typedef __attribute__((address_space(3))) void lds_void;
__device__ __forceinline__ void gl_lds16(const void* g, void* l) {
  // async global->LDS, 16B per lane; LDS dest = wave-uniform base + lane*16
  __builtin_amdgcn_global_load_lds((gconst_void*)g, (lds_void*)l, 16, 0, 0);
}

// ---------------- fused weight prep (all 4 weight matrices + biases) ----------------
__global__ __launch_bounds__(256) void prep_w(
    const float* __restrict__ Wq, const float* __restrict__ Wk,
    const float* __restrict__ Wv_sh, const float* __restrict__ Wv_sp,
    const float* __restrict__ Wo_sh, const float* __restrict__ Wo_sp,
    const float* __restrict__ bv_sh, const float* __restrict__ bv_sp,
    const float* __restrict__ bo_sh, const float* __restrict__ bo_sp,
    const int* __restrict__ langp,
    u16* __restrict__ Wq_b, u16* __restrict__ Wk_b,
    u16* __restrict__ Wv_b, u16* __restrict__ Wo_b,
    float* __restrict__ bv_f, float* __restrict__ bo_f) {
  int lang = langp[0];
  int i = blockIdx.x * 256 + threadIdx.x;           // over E_*E_/4
  size_t wofs = (size_t)lang * (E_*E_/4) + i;
  ((ushort4*)Wq_b)[i] = f2bf4(((const float4*)Wq)[i]);
  ((ushort4*)Wk_b)[i] = f2bf4(((const float4*)Wk)[i]);
  float4 vs = ((const float4*)Wv_sh)[i], vp = ((const float4*)Wv_sp)[wofs];
  float4 os = ((const float4*)Wo_sh)[i], op = ((const float4*)Wo_sp)[wofs];
  float4 vv = {vs.x*vp.x, vs.y*vp.y, vs.z*vp.z, vs.w*vp.w};
  float4 oo = {os.x*op.x, os.y*op.y, os.z*op.z, os.w*op.w};
  ((ushort4*)Wv_b)[i] = f2bf4(vv);
  ((ushort4*)Wo_b)[i] = f2bf4(oo);
  if (i < E_/4) {
    float4 b1 = ((const float4*)bv_sh)[i], b2 = ((const float4*)(bv_sp + (size_t)lang*E_))[i];
    float4 b3 = ((const float4*)bo_sh)[i], b4 = ((const float4*)(bo_sp + (size_t)lang*E_))[i];
    float4 r1 = {b1.x+b2.x, b1.y+b2.y, b1.z+b2.z, b1.w+b2.w};
    float4 r2 = {b3.x+b4.x, b3.y+b4.y, b3.z+b4.z, b3.w+b4.w};
    ((float4*)bv_f)[i] = r1;
    ((float4*)bo_f)[i] = r2;
  }
}

// ---------------- fused QKV projection GEMM, BK=64 (two 32-col panels) ----------------
// blockIdx.z selects {q,k,v}. A fp32 staged via global_load_lds; bf16 convert on
// fragment read. z==2 (V) writes DIRECTLY in transposed layout Vt[(b*E+e)][s].
__global__ __launch_bounds__(256) void gemm_qkv(
    const float* __restrict__ q, const float* __restrict__ k, const float* __restrict__ v,
    const u16* __restrict__ Wq_b, const u16* __restrict__ Wk_b, const u16* __restrict__ Wv_b,
    const float* __restrict__ bq, const float* __restrict__ bk, const float* __restrict__ bv,
    u16* __restrict__ Qb, u16* __restrict__ Kb, u16* __restrict__ Vt) {
  __shared__ __align__(16) float sAf[2*128*32];   // 32 KB, panel p at p*4096
  __shared__ __align__(16) u16 sB[2*128*32];      // 16 KB, panel p at p*4096
  const int z = blockIdx.z;
  const float* A    = (z == 0) ? q : (z == 1) ? k : v;
  const u16*   Bw   = (z == 0) ? Wq_b : (z == 1) ? Wk_b : Wv_b;
  const float* bias = (z == 0) ? bq : (z == 1) ? bk : bv;
  const int t = threadIdx.x;
  const int m0 = blockIdx.y * 128, n0 = blockIdx.x * 128;
  const int lane = t & 63, wid = t >> 6;
  const int m16 = lane & 15, qq = lane >> 4;
  const int wrow = (wid >> 1) * 64, wcol = (wid & 1) * 64;
  f32x4 acc[4][4] = {};
  // A staging: chunk = 8 rows x 32 floats (1KB); lane -> row +(l>>3), col (l&7)*4
  const float* apg[2][4];
  float* apl[2][4];
#pragma unroll
  for (int p = 0; p < 2; ++p)
#pragma unroll
    for (int i = 0; i < 4; ++i) {
      int ca = wid*4 + i;
      apg[p][i] = A + (size_t)(m0 + ca*8 + (lane >> 3)) * E_ + p*32 + (lane & 7) * 4;
      apl[p][i] = &sAf[p*4096 + ca*256 + lane*4];
    }
  // B staging: chunk = 16 rows x 32 u16 (1KB); lane -> row +(l>>2), col (l&3)*8
  const u16* bpg[2][2];
  u16* bpl[2][2];
#pragma unroll
  for (int p = 0; p < 2; ++p)
#pragma unroll
    for (int i = 0; i < 2; ++i) {
      int cb = wid*2 + i;
      bpg[p][i] = Bw + (size_t)(n0 + cb*16 + (lane >> 2)) * E_ + p*32 + (lane & 3) * 8;
      bpl[p][i] = &sB[p*4096 + cb*512 + lane*8];
    }
  for (int k0 = 0; k0 < E_; k0 += 64) {
#pragma unroll
    for (int p = 0; p < 2; ++p) {
#pragma unroll
      for (int i = 0; i < 4; ++i) gl_lds16(apg[p][i], apl[p][i]);
#pragma unroll
      for (int i = 0; i < 2; ++i) gl_lds16(bpg[p][i], bpl[p][i]);
    }
    __syncthreads();   // drains vmcnt -> LDS data visible
#pragma unroll
    for (int p = 0; p < 2; ++p) {
      bf16x8 af[4], bfm[4];
#pragma unroll
      for (int mt = 0; mt < 4; ++mt) {
        const float* ar = &sAf[p*4096 + (wrow + mt*16 + m16) * 32 + qq*8];
        f32x4 a0 = *(const f32x4*)ar;
        f32x4 a1 = *(const f32x4*)(ar + 4);
        union { uint4v u; bf16x8 h; } cv;
        cv.u = (uint4v){ pk_bf16(a0[0], a0[1]), pk_bf16(a0[2], a0[3]),
                         pk_bf16(a1[0], a1[1]), pk_bf16(a1[2], a1[3]) };
        af[mt] = cv.h;
      }
#pragma unroll
      for (int nt = 0; nt < 4; ++nt)
        bfm[nt] = *(const bf16x8*)&sB[p*4096 + (wcol + nt*16 + m16) * 32 + qq*8];
#pragma unroll
      for (int mt = 0; mt < 4; ++mt)
#pragma unroll
        for (int nt = 0; nt < 4; ++nt)
          acc[mt][nt] = __builtin_amdgcn_mfma_f32_16x16x32_bf16(af[mt], bfm[nt], acc[mt][nt], 0, 0, 0);
    }
    __syncthreads();
#pragma unroll
    for (int p = 0; p < 2; ++p) {
#pragma unroll
      for (int i = 0; i < 4; ++i) apg[p][i] += 64;
#pragma unroll
      for (int i = 0; i < 2; ++i) bpg[p][i] += 64;
    }
  }
  float bvv[4];
#pragma unroll
  for (int nt = 0; nt < 4; ++nt) bvv[nt] = bias[n0 + wcol + nt*16 + m16];
  if (z < 2) {
    u16* out = (z == 0) ? Qb : Kb;
#pragma unroll
    for (int mt = 0; mt < 4; ++mt) {
      int gm = m0 + wrow + mt*16 + qq*4;   // C/D: row = quad*4 + reg
#pragma unroll
      for (int nt = 0; nt < 4; ++nt) {
        int gn = n0 + wcol + nt*16 + m16;  // C/D: col = lane&15
#pragma unroll
        for (int r = 0; r < 4; ++r)
          out[(size_t)(gm + r) * E_ + gn] = f2bf(acc[mt][nt][r] + bvv[nt]);
      }
    }
  } else {
    // V: write transposed Vt[(b*E + gn)][s]; 4 consecutive s per lane -> ushort4
#pragma unroll
    for (int mt = 0; mt < 4; ++mt) {
      int gm = m0 + wrow + mt*16 + qq*4;
      int b = gm >> 10, s0 = gm & (S_ - 1);   // 128-row tiles never cross batch
#pragma unroll
      for (int nt = 0; nt < 4; ++nt) {
        int gn = n0 + wcol + nt*16 + m16;
        ushort4 u;
        u.x = f2bf(acc[mt][nt][0] + bvv[nt]);
        u.y = f2bf(acc[mt][nt][1] + bvv[nt]);
        u.z = f2bf(acc[mt][nt][2] + bvv[nt]);
        u.w = f2bf(acc[mt][nt][3] + bvv[nt]);
        *(ushort4*)&Vt[((size_t)(b*E_ + gn)) * S_ + s0] = u;
      }
    }
  }
}

// ---------------- bf16 MFMA GEMM, BK=64: out = A @ Bw^T + bias (fp32 out) ----------------
__global__ __launch_bounds__(256) void gemm_lds(
    const u16* __restrict__ A, const u16* __restrict__ Bw,
    const float* __restrict__ bias, float* __restrict__ out) {
  __shared__ __align__(16) u16 sA[2*128*32];
  __shared__ __align__(16) u16 sB[2*128*32];
  const int t = threadIdx.x;
  const int m0 = blockIdx.y * 128, n0 = blockIdx.x * 128;
  const int lane = t & 63, wid = t >> 6;
  const int m16 = lane & 15, qq = lane >> 4;
  const int wrow = (wid >> 1) * 64, wcol = (wid & 1) * 64;
  f32x4 acc[4][4] = {};
  const u16* apg[2][2]; u16* apl[2][2];
  const u16* bpg[2][2]; u16* bpl[2][2];
#pragma unroll
  for (int p = 0; p < 2; ++p)
#pragma unroll
    for (int i = 0; i < 2; ++i) {
      int c = wid*2 + i;
      apg[p][i] = A  + (size_t)(m0 + c*16 + (lane >> 2)) * E_ + p*32 + (lane & 3) * 8;
      bpg[p][i] = Bw + (size_t)(n0 + c*16 + (lane >> 2)) * E_ + p*32 + (lane & 3) * 8;
      apl[p][i] = &sA[p*4096 + c*512 + lane*8];
      bpl[p][i] = &sB[p*4096 + c*512 + lane*8];
    }
  for (int k0 = 0; k0 < E_; k0 += 64) {
#pragma unroll
    for (int p = 0; p < 2; ++p)
#pragma unroll
      for (int i = 0; i < 2; ++i) {
        gl_lds16(apg[p][i], apl[p][i]);
        gl_lds16(bpg[p][i], bpl[p][i]);
      }
    __syncthreads();
#pragma unroll
    for (int p = 0; p < 2; ++p) {
      bf16x8 af[4], bfm[4];
#pragma unroll
      for (int mt = 0; mt < 4; ++mt)
        af[mt] = *(const bf16x8*)&sA[p*4096 + (wrow + mt*16 + m16) * 32 + qq*8];
#pragma unroll
      for (int nt = 0; nt < 4; ++nt)
        bfm[nt] = *(const bf16x8*)&sB[p*4096 + (wcol + nt*16 + m16) * 32 + qq*8];
#pragma unroll
      for (int mt = 0; mt < 4; ++mt)
#pragma unroll
        for (int nt = 0; nt < 4; ++nt)
          acc[mt][nt] = __builtin_amdgcn_mfma_f32_16x16x32_bf16(af[mt], bfm[nt], acc[mt][nt], 0, 0, 0);
    }
    __syncthreads();
#pragma unroll
    for (int p = 0; p < 2; ++p)
#pragma unroll
      for (int i = 0; i < 2; ++i) { apg[p][i] += 64; bpg[p][i] += 64; }
  }
  float bv[4];
#pragma unroll
  for (int nt = 0; nt < 4; ++nt) bv[nt] = bias[n0 + wcol + nt*16 + m16];
#pragma unroll
  for (int mt = 0; mt < 4; ++mt) {
    int gm = m0 + wrow + mt*16 + qq*4;
#pragma unroll
    for (int nt = 0; nt < 4; ++nt) {
      int gn = n0 + wcol + nt*16 + m16;
#pragma unroll
      for (int r = 0; r < 4; ++r)
        out[(size_t)(gm + r) * E_ + gn] = acc[mt][nt][r] + bv[nt];
    }
  }
}

// ---------------- MFMA flash attention: Q-tile 128, 32 q-rows/wave ----------------
// Block = (b,h, 128 q-rows); wave w owns rows [w*32, w*32+32) as 2 fragments.
// S^T = mfma(K, Q): lane holds 4 consecutive keys of one q-row -> packed b64 P.
// Fixed-shift softmax (scores bounded; masked -> exp2(-1e9)=0); l deferred.
#define KST 72   // padded LDS row stride (u16)
__global__ __launch_bounds__(256) void attn_mfma(
    const u16* __restrict__ Qb, const u16* __restrict__ Kb, const u16* __restrict__ Vt,
    const int* __restrict__ mask, u16* __restrict__ ctxb) {
  __shared__ __align__(16) u16 sK[64*KST];
  __shared__ __align__(16) u16 sV[64*KST];    // V^T tile: row=dim, col=key
  __shared__ __align__(16) u16 sP[128*KST];   // P tile (also final O staging)
  __shared__ __align__(16) float sMask[64];
  __shared__ __align__(16) float sL[128];
  const int t = threadIdx.x;
  const int lane = t & 63, w = t >> 6;
  const int m16 = lane & 15, quad = lane >> 4;
  const int bh = blockIdx.y, b = bh >> 3, h = bh & 7;
  const int qblk = blockIdx.x * 128;
  const int q0 = qblk + w * 32;
  bf16x8 qf[2][2];   // B-operand: n=lane&15=qrow, k=quad*8+j; 2 frags x 2 k-steps
#pragma unroll
  for (int f = 0; f < 2; ++f) {
    const u16* qp = Qb + (size_t)(b*S_ + q0 + f*16 + m16) * E_ + h*D_ + quad*8;
    qf[f][0] = *(const bf16x8*)qp;
    qf[f][1] = *(const bf16x8*)(qp + 32);
  }
  f32x4 oacc[2][4] = {};
  float lpart[2] = {0.f, 0.f};
  const int srow = t >> 2, sc0 = (t & 3) * 16;
  const u16* kp = Kb + (size_t)(b*S_ + srow) * E_ + h*D_ + sc0;
  const u16* vp = Vt + ((size_t)(b*E_ + h*D_) + srow) * S_ + sc0;
  uint4 rk0 = *(const uint4*)kp, rk1 = *(const uint4*)(kp + 8);
  uint4 rv0 = *(const uint4*)vp, rv1 = *(const uint4*)(vp + 8);
  float rmsk = 0.f;
  if (t < 64) rmsk = (mask[b*S_ + t] == 0) ? -1e9f : 0.f;
  const float CS = 0.015625f * 1.44269504f;   // (1/64)*log2(e)
  for (int kt = 0; kt < S_; kt += 64) {
    *(uint4*)&sK[srow*KST + sc0]     = rk0;
    *(uint4*)&sK[srow*KST + sc0 + 8] = rk1;
    *(uint4*)&sV[srow*KST + sc0]     = rv0;
    *(uint4*)&sV[srow*KST + sc0 + 8] = rv1;
    if (t < 64) sMask[t] = rmsk;
    __syncthreads();
    if (kt + 64 < S_) {   // prefetch next tile behind this tile's compute
      kp += (size_t)64 * E_; vp += 64;
      rk0 = *(const uint4*)kp; rk1 = *(const uint4*)(kp + 8);
      rv0 = *(const uint4*)vp; rv1 = *(const uint4*)(vp + 8);
      if (t < 64) rmsk = (mask[b*S_ + kt + 64 + t] == 0) ? -1e9f : 0.f;
    }
    // ---- S^T = K Q^T : A=K (m=key), B=Q-frag (n=qrow); kf shared by both frags ----
    f32x4 sacc[2][4] = {};
#pragma unroll
    for (int ct = 0; ct < 4; ++ct) {
      bf16x8 kf0 = *(const bf16x8*)&sK[(ct*16 + m16)*KST + quad*8];
      bf16x8 kf1 = *(const bf16x8*)&sK[(ct*16 + m16)*KST + 32 + quad*8];
      sacc[0][ct] = __builtin_amdgcn_mfma_f32_16x16x32_bf16(kf0, qf[0][0], sacc[0][ct], 0, 0, 0);
      sacc[0][ct] = __builtin_amdgcn_mfma_f32_16x16x32_bf16(kf1, qf[0][1], sacc[0][ct], 0, 0, 0);
      sacc[1][ct] = __builtin_amdgcn_mfma_f32_16x16x32_bf16(kf0, qf[1][0], sacc[1][ct], 0, 0, 0);
      sacc[1][ct] = __builtin_amdgcn_mfma_f32_16x16x32_bf16(kf1, qf[1][1], sacc[1][ct], 0, 0, 0);
    }
    // ---- softmax: lane has keys ct*16+quad*4+r of q-row f*16+m16 ----
#pragma unroll
    for (int f = 0; f < 2; ++f) {
#pragma unroll
      for (int ct = 0; ct < 4; ++ct) {
        f32x4 msk = *(const f32x4*)&sMask[ct*16 + quad*4];
        float p0 = exp2f(fmaf(sacc[f][ct][0], CS, msk[0]));
        float p1 = exp2f(fmaf(sacc[f][ct][1], CS, msk[1]));
        float p2 = exp2f(fmaf(sacc[f][ct][2], CS, msk[2]));
        float p3 = exp2f(fmaf(sacc[f][ct][3], CS, msk[3]));
        lpart[f] += (p0 + p1) + (p2 + p3);
        uint2 pq = { pk_bf16(p0, p1), pk_bf16(p2, p3) };
        *(uint2*)&sP[(w*32 + f*16 + m16)*KST + ct*16 + quad*4] = pq;  // wave-private
      }
    }
    bf16x8 pf[2][2];
#pragma unroll
    for (int f = 0; f < 2; ++f) {
      pf[f][0] = *(const bf16x8*)&sP[(w*32 + f*16 + m16)*KST + quad*8];
      pf[f][1] = *(const bf16x8*)&sP[(w*32 + f*16 + m16)*KST + 32 + quad*8];
    }
    // ---- O += P V : A=P (m=qrow), B=V^T (n=dim); vf shared by both frags ----
#pragma unroll
    for (int dt = 0; dt < 4; ++dt) {
      bf16x8 vf0 = *(const bf16x8*)&sV[(dt*16 + m16)*KST + quad*8];
      bf16x8 vf1 = *(const bf16x8*)&sV[(dt*16 + m16)*KST + 32 + quad*8];
      oacc[0][dt] = __builtin_amdgcn_mfma_f32_16x16x32_bf16(pf[0][0], vf0, oacc[0][dt], 0, 0, 0);
      oacc[0][dt] = __builtin_amdgcn_mfma_f32_16x16x32_bf16(pf[0][1], vf1, oacc[0][dt], 0, 0, 0);
      oacc[1][dt] = __builtin_amdgcn_mfma_f32_16x16x32_bf16(pf[1][0], vf0, oacc[1][dt], 0, 0, 0);
      oacc[1][dt] = __builtin_amdgcn_mfma_f32_16x16x32_bf16(pf[1][1], vf1, oacc[1][dt], 0, 0, 0);
    }
    __syncthreads();   // all waves done reading sK/sV before next staging
  }
  // ---- deferred l reduction (lane's lpart is for qrow f*16+m16) ----
#pragma unroll
  for (int f = 0; f < 2; ++f) {
    float l = lpart[f];
    l += __shfl_xor(l, 16);
    l += __shfl_xor(l, 32);
    if (quad == 0) sL[w*32 + f*16 + m16] = l;   // wave-private broadcast
  }
  // oacc C-layout: row(qrow)=quad*4+r, col(dim)=dt*16+m16
#pragma unroll
  for (int f = 0; f < 2; ++f) {
    float inv[4];
#pragma unroll
    for (int r = 0; r < 4; ++r) inv[r] = 1.0f / sL[w*32 + f*16 + quad*4 + r];
#pragma unroll
    for (int dt = 0; dt < 4; ++dt)
#pragma unroll
      for (int r = 0; r < 4; ++r)
        sP[(w*32 + f*16 + quad*4 + r)*KST + dt*16 + m16] = f2bf(oacc[f][dt][r] * inv[r]);
  }
  __syncthreads();
  const int orow = t >> 1, oc0 = (t & 1) * 32;
  uint4 o0 = *(uint4*)&sP[orow*KST + oc0];
  uint4 o1 = *(uint4*)&sP[orow*KST + oc0 + 8];
  uint4 o2 = *(uint4*)&sP[orow*KST + oc0 + 16];
  uint4 o3 = *(uint4*)&sP[orow*KST + oc0 + 24];
  u16* dst = ctxb + (size_t)(b*S_ + qblk + orow) * E_ + h*D_ + oc0;
  *(uint4*)dst = o0;
  *(uint4*)(dst + 8) = o1;
  *(uint4*)(dst + 16) = o2;
  *(uint4*)(dst + 24) = o3;
}

// ---------------- launch ----------------
extern "C" void kernel_launch(void* const* d_in, const int* in_sizes, int n_in,
                              void* d_out, int out_size, void* d_ws, size_t ws_size,
                              hipStream_t stream) {
  const float* q     = (const float*)d_in[0];
  const float* k     = (const float*)d_in[1];
  const float* v     = (const float*)d_in[2];
  const float* Wq    = (const float*)d_in[3];
  const float* bq    = (const float*)d_in[4];
  const float* Wk    = (const float*)d_in[5];
  const float* bk    = (const float*)d_in[6];
  const float* Wv_sh = (const float*)d_in[7];
  const float* Wv_sp = (const float*)d_in[8];
  const float* bv_sh = (const float*)d_in[9];
  const float* bv_sp = (const float*)d_in[10];
  const float* Wo_sh = (const float*)d_in[11];
  const float* Wo_sp = (const float*)d_in[12];
  const float* bo_sh = (const float*)d_in[13];
  const float* bo_sp = (const float*)d_in[14];
  const int*   mask  = (const int*)d_in[15];
  const int*   lang  = (const int*)d_in[16];

  char* ws = (char*)d_ws;
  size_t off = 0;
  auto alloc = [&](size_t bytes) -> char* {
    char* p = ws + off;
    off += (bytes + 255) & ~(size_t)255;
    return p;
  };
  u16* Qb   = (u16*)alloc((size_t)M_ * E_ * 2);
  u16* Kb   = (u16*)alloc((size_t)M_ * E_ * 2);
  u16* Vt   = (u16*)alloc((size_t)M_ * E_ * 2);
  u16* ctxb = (u16*)alloc((size_t)M_ * E_ * 2);
  u16* Wq_b = (u16*)alloc((size_t)E_ * E_ * 2);
  u16* Wk_b = (u16*)alloc((size_t)E_ * E_ * 2);
  u16* Wv_b = (u16*)alloc((size_t)E_ * E_ * 2);
  u16* Wo_b = (u16*)alloc((size_t)E_ * E_ * 2);
  float* bv_f = (float*)alloc(E_ * 4);
  float* bo_f = (float*)alloc(E_ * 4);

  prep_w<<<E_*E_/1024, 256, 0, stream>>>(Wq, Wk, Wv_sh, Wv_sp, Wo_sh, Wo_sp,
                                         bv_sh, bv_sp, bo_sh, bo_sp, lang,
                                         Wq_b, Wk_b, Wv_b, Wo_b, bv_f, bo_f);

  dim3 qkvgrid(E_/128, M_/128, 3);   // (4, 128, 3) = 1536 blocks
  gemm_qkv<<<qkvgrid, 256, 0, stream>>>(q, k, v, Wq_b, Wk_b, Wv_b,
                                        bq, bk, bv_f, Qb, Kb, Vt);

  dim3 agrid(S_/128, B_*H_);    // (8, 128) = 1024 blocks
  attn_mfma<<<agrid, 256, 0, stream>>>(Qb, Kb, Vt, mask, ctxb);

  dim3 ggrid(E_/128, M_/128);   // (4, 128)
  gemm_lds<<<ggrid, 256, 0, stream>>>(ctxb, Wo_b, bo_f, (float*)d_out);
}